// Round 16
// baseline (396.761 us; speedup 1.0000x reference)
//
#include <hip/hip_runtime.h>
#include <math.h>

#define NB 65536

typedef __attribute__((ext_vector_type(8))) short bf16x8;
typedef __attribute__((ext_vector_type(4))) float f32x4;

// ---- ws byte offsets ----
#define O_BIAST  0         // f32 [7][96]                 2688
#define O_FC1C   4096      // f32 [192]
#define O_FC1BP  8192      // f32 [192]
#define O_FC1FR  12288     // u16 [72][64][8]   73728  -> 86016
#define O_FC2FR  86016     // u16 [36][64][8]   36864  -> 122880
#define O_HDFR   122880    // u16 [330][64][8]  337920 -> 460800
#define O_HDC    460800    // f32 [480]
#define O_HDBP   462848    // f32 [480]
#define O_W2C    464896    // f32 [480]
#define O_SPC    466944    // f32 [128]
#define O_SPB    467968    // f32 [128]
#define O_SP1FR  468992    // u16 [16][64][8]   16384  -> 485376
#define O_SP2FR  485376    // u16 [16][64][8]   16384  -> 501760
#define O_XP2FR  501760    // u16 [54][64][8]   55296  -> 557056
#define O_EMB16  557056    // u16 [16][101][16] 51712  -> 608768
#define O_FEAT   608768    // (unused now)
#define O_S64    38357504  // u16 [65536][64]   8388608  -> 46746112
#define O_STAT   46746112  // f32 [65536][2]    524288   -> 47270400
#define O_BASE   47270400  // f32 [65536]       262144   -> 47532544
#define O_XROW   47532544  // u16 [458752][96]  88080384 -> 135612928
#define O_XSTAT  135612928 // f32 [458752][2]   3670016  -> 139282944

__device__ __forceinline__ unsigned short f2b(float x) {
  unsigned int u = __float_as_uint(x);
  u += 0x7fffu + ((u >> 16) & 1u);   // RNE bf16
  return (unsigned short)(u >> 16);
}
__device__ __forceinline__ float b2f(unsigned short u) {
  return __uint_as_float(((unsigned)u) << 16);
}
// tanh-form GELU, branch-free (round-9 proven: absmax unchanged)
__device__ __forceinline__ float geluf(float x) {
  float z = x * x;
  float e = __builtin_amdgcn_exp2f(-x * (2.3022137f + 0.10294456f * z));
  return x * __builtin_amdgcn_rcpf(1.0f + e);
}

// head LN-fold, 4-way k-split: part covers cols part*120..+119, 4 lanes/col
__device__ __forceinline__ void head_fold_part(
    int part, int tid,
    const float* __restrict__ hln_g, const float* __restrict__ hln_b,
    const float* __restrict__ hm1_w, const float* __restrict__ hm1_b,
    const float* __restrict__ hq1_w, const float* __restrict__ hq1_b,
    const float* __restrict__ hn1_w, const float* __restrict__ hn1_b,
    const float* __restrict__ hm2_w, const float* __restrict__ hq2_w,
    const float* __restrict__ hn2_w, char* __restrict__ wsb)
{
  if (tid >= 480) return;
  const int gcol = part*120 + (tid >> 2);
  const int ksl = tid & 3;
  float C = 0.f, Bp = 0.f;
  for (int j = 0; j < 88; ++j) {
    int k = ksl*88 + j;
    float w;
    if (gcol < 192) w = hm1_w[k*192 + gcol];
    else if (gcol < 384) w = hq1_w[k*192 + (gcol-192)];
    else w = hn1_w[k*96 + (gcol-384)];
    C = fmaf(hln_g[k], w, C);
    Bp = fmaf(hln_b[k], w, Bp);
  }
  C += __shfl_xor(C, 1, 64); C += __shfl_xor(C, 2, 64);
  Bp += __shfl_xor(Bp, 1, 64); Bp += __shfl_xor(Bp, 2, 64);
  if (ksl == 0) {
    float b0, w2;
    if (gcol < 192) { b0 = hm1_b[gcol]; w2 = hm2_w[gcol]; }
    else if (gcol < 384) { b0 = hq1_b[gcol-192]; w2 = hq2_w[gcol-192]; }
    else { b0 = hn1_b[gcol-384]; w2 = hn2_w[gcol-384]; }
    ((float*)(wsb + O_HDC))[gcol] = C;
    ((float*)(wsb + O_HDBP))[gcol] = Bp + b0;
    ((float*)(wsb + O_W2C))[gcol] = w2;
  }
}

// =================== K0: fold + frag-pack all weights ===================
__global__ void k0_pre(
    const float* __restrict__ cat_emb, const float* __restrict__ day_emb,
    const float* __restrict__ xproj_w, const float* __restrict__ xproj_b,
    const float* __restrict__ bln_g, const float* __restrict__ bln_b,
    const float* __restrict__ fc1_w, const float* __restrict__ fc1_b,
    const float* __restrict__ fc2_w,
    const float* __restrict__ spln_g, const float* __restrict__ spln_b,
    const float* __restrict__ sp1_w, const float* __restrict__ sp1_b,
    const float* __restrict__ sp2_w,
    const float* __restrict__ hln_g, const float* __restrict__ hln_b,
    const float* __restrict__ hm1_w, const float* __restrict__ hm1_b,
    const float* __restrict__ hq1_w, const float* __restrict__ hq1_b,
    const float* __restrict__ hn1_w, const float* __restrict__ hn1_b,
    const float* __restrict__ hm2_w, const float* __restrict__ hq2_w,
    const float* __restrict__ hn2_w,
    char* __restrict__ wsb)
{
  const int b = blockIdx.x, tid = threadIdx.x;
  if (b < 7) {                        // per-t bias (xproj_b + day part)
    if (tid < 96) {
      int t = b;
      float acc = xproj_b[tid];
      #pragma unroll
      for (int d = 0; d < 8; ++d)
        acc = fmaf(day_emb[(1+t)*8 + d], xproj_w[(288+d)*96 + tid], acc);
      ((float*)(wsb + O_BIAST))[t*96 + tid] = acc;
    }
  } else if (b < 9) {                 // fc1 LN-fold C / B' (4-way k-split)
    if (tid < 384) {
      int col = (b-7)*96 + (tid >> 2);
      int ksl = tid & 3;
      float C = 0.f, Bp = 0.f;
      for (int j = 0; j < 48; ++j) {
        int k = ksl*48 + j;
        float w = fc1_w[k*192 + col];
        C = fmaf(bln_g[k], w, C);
        Bp = fmaf(bln_b[k], w, Bp);
      }
      C += __shfl_xor(C, 1, 64); C += __shfl_xor(C, 2, 64);
      Bp += __shfl_xor(Bp, 1, 64); Bp += __shfl_xor(Bp, 2, 64);
      if (ksl == 0) {
        ((float*)(wsb + O_FC1C))[col] = C;
        ((float*)(wsb + O_FC1BP))[col] = Bp + fc1_b[col];
      }
    }
  } else if (b < 81) {                // fc1 frags [nt(12)][ks(6)]
    int seg = b - 9, nt = seg / 6, ks = seg - nt*6;
    int ln = tid >> 3, j = tid & 7;
    int k = ks*32 + (ln>>4)*8 + j, col = nt*16 + (ln&15);
    ((unsigned short*)(wsb + O_FC1FR))[(seg*64 + ln)*8 + j] = f2b(bln_g[k]*fc1_w[k*192 + col]);
  } else if (b < 117) {               // fc2 frags [nt(6)][ks(6)]
    int seg = b - 81, nt = seg / 6, ks = seg - nt*6;
    int ln = tid >> 3, j = tid & 7;
    int k = ks*32 + (ln>>4)*8 + j, col = nt*16 + (ln&15);
    ((unsigned short*)(wsb + O_FC2FR))[(seg*64 + ln)*8 + j] = f2b(fc2_w[k*96 + col]);
  } else if (b < 447) {               // head frags [nt(30)][ks(11)]
    int seg = b - 117, nt = seg / 11, ks = seg - nt*11;
    int ln = tid >> 3, j = tid & 7;
    int k = ks*32 + (ln>>4)*8 + j, gcol = nt*16 + (ln&15);
    float w;
    if (gcol < 192) w = hm1_w[k*192 + gcol];
    else if (gcol < 384) w = hq1_w[k*192 + (gcol-192)];
    else w = hn1_w[k*96 + (gcol-384)];
    ((unsigned short*)(wsb + O_HDFR))[(seg*64 + ln)*8 + j] = f2b(hln_g[k]*w);
  } else if (b < 448) {               // head fold part 0 (cols 0..119)
    head_fold_part(0, tid, hln_g, hln_b, hm1_w, hm1_b, hq1_w, hq1_b,
                   hn1_w, hn1_b, hm2_w, hq2_w, hn2_w, wsb);
  } else if (b < 449) {               // sp1 LN-fold (C from bf16-rounded weights)
    if (tid < 128) {
      int col = tid;
      float C = 0.f, Bp = sp1_b[col];
      for (int k = 0; k < 64; ++k) {
        float w = sp1_w[k*128 + col];
        C += b2f(f2b(spln_g[k]*w));
        Bp = fmaf(spln_b[k], w, Bp);
      }
      ((float*)(wsb + O_SPC))[col] = C;
      ((float*)(wsb + O_SPB))[col] = Bp;
    }
  } else if (b < 465) {               // sp1 frags [nt(8)][ks(2)]
    int seg = b - 449;
    int ln = tid >> 3, j = tid & 7;
    int nt = seg >> 1, ks = seg & 1;
    int k = ks*32 + (ln>>4)*8 + j, col = nt*16 + (ln&15);
    ((unsigned short*)(wsb + O_SP1FR))[(seg*64 + ln)*8 + j] = f2b(spln_g[k]*sp1_w[k*128 + col]);
  } else if (b < 481) {               // sp2 frags [nt(4)][ks(4)]
    int seg = b - 465;
    int ln = tid >> 3, j = tid & 7;
    int ks = seg & 3;
    int k = ks*32 + (ln>>4)*8 + j, col = (seg >> 2)*16 + (ln&15);
    ((unsigned short*)(wsb + O_SP2FR))[(seg*64 + ln)*8 + j] = f2b(sp2_w[k*64 + col]);
  } else if (b < 535) {               // xproj K=288 frags [ks(9)][nt(6)]
    int seg = b - 481, ks = seg / 6, nt = seg - ks*6;
    int ln = tid >> 3, j = tid & 7;
    int k = ks*32 + (ln>>4)*8 + j, col = nt*16 + (ln&15);
    ((unsigned short*)(wsb + O_XP2FR))[(seg*64 + ln)*8 + j] = f2b(xproj_w[k*96 + col]);
  } else if (b < 586) {               // raw emb table -> bf16 [16][101][16]
    int i = (b - 535)*512 + tid;
    if (i < 25856)
      ((unsigned short*)(wsb + O_EMB16))[i] = f2b(cat_emb[i]);
  } else {                            // head fold parts 1..3 (b = 586..588)
    head_fold_part(b - 585, tid, hln_g, hln_b, hm1_w, hm1_b, hq1_w, hq1_b,
                   hn1_w, hn1_b, hm2_w, hq2_w, hn2_w, wsb);
  }
}

// =================== K1ab: fused x-projection + static MLP ===================
__global__ __launch_bounds__(256) void k1ab(
    const float* __restrict__ x_num, const int* __restrict__ x_cat,
    const float* __restrict__ x_static, const float* __restrict__ sp2_b,
    const float* __restrict__ base_w, const float* __restrict__ base_b,
    char* __restrict__ wsb, unsigned short* __restrict__ xrow,
    float* __restrict__ xstat)
{
  __shared__ char smem[28288];   // k1a: ctile(25600)+bsh(2688); k1b: hid(17408)
  const int tid = threadIdx.x;
  const int wv = tid >> 6, l = tid & 63, lr = l & 15, lq = l >> 4;
  const f32x4 zero4 = {0.f, 0.f, 0.f, 0.f};

  if (blockIdx.x >= 3584) {
    // ============ static-MLP role ============
    unsigned short* hid = (unsigned short*)smem;
    const int srow = (blockIdx.x - 3584)*64 + wv*16;

    float x0f[8], x1f[8];
    {
      const float* xr = x_static + (size_t)(srow + lr)*64;
      *(float4*)&x0f[0] = *(const float4*)(xr + lq*8);
      *(float4*)&x0f[4] = *(const float4*)(xr + lq*8 + 4);
      *(float4*)&x1f[0] = *(const float4*)(xr + 32 + lq*8);
      *(float4*)&x1f[4] = *(const float4*)(xr + 32 + lq*8 + 4);
    }
    float sm = 0.f, sq = 0.f, bp = 0.f;
    #pragma unroll
    for (int j = 0; j < 8; ++j) {
      sm += x0f[j] + x1f[j];
      sq = fmaf(x0f[j], x0f[j], fmaf(x1f[j], x1f[j], sq));
      bp = fmaf(x0f[j], base_w[lq*8 + j], fmaf(x1f[j], base_w[32 + lq*8 + j], bp));
    }
    sm += __shfl_xor(sm, 16, 64); sm += __shfl_xor(sm, 32, 64);
    sq += __shfl_xor(sq, 16, 64); sq += __shfl_xor(sq, 32, 64);
    bp += __shfl_xor(bp, 16, 64); bp += __shfl_xor(bp, 32, 64);
    if (lq == 0) ((float*)(wsb + O_BASE))[srow + lr] = bp + base_b[0];
    const float ms = sm*(1.f/64.f);
    const float rs = rsqrtf(sq*(1.f/64.f) - ms*ms + 1e-5f);
    float mr[4], rr[4];
    #pragma unroll
    for (int i = 0; i < 4; ++i) {
      mr[i] = __shfl(ms, lq*4 + i, 16);
      rr[i] = __shfl(rs, lq*4 + i, 16);
    }
    union { bf16x8 v; unsigned short u[8]; } ua0, ua1;
    #pragma unroll
    for (int j = 0; j < 8; ++j) { ua0.u[j] = f2b(x0f[j]); ua1.u[j] = f2b(x1f[j]); }

    const bf16x8* f1 = (const bf16x8*)(wsb + O_SP1FR);
    const bf16x8* f2 = (const bf16x8*)(wsb + O_SP2FR);
    unsigned short* hw = hid + wv*2176;

    f32x4 acc[8];
    #pragma unroll
    for (int nt = 0; nt < 8; ++nt) acc[nt] = zero4;
    #pragma unroll
    for (int nt = 0; nt < 8; ++nt) {
      acc[nt] = __builtin_amdgcn_mfma_f32_16x16x32_bf16(ua0.v, f1[(nt*2 + 0)*64 + l], acc[nt], 0, 0, 0);
      acc[nt] = __builtin_amdgcn_mfma_f32_16x16x32_bf16(ua1.v, f1[(nt*2 + 1)*64 + l], acc[nt], 0, 0, 0);
    }
    {
      const float* spC = (const float*)(wsb + O_SPC);
      const float* spB = (const float*)(wsb + O_SPB);
      #pragma unroll
      for (int nt = 0; nt < 8; ++nt) {
        float Cv = spC[nt*16 + lr], Bv = spB[nt*16 + lr];
        #pragma unroll
        for (int i = 0; i < 4; ++i) {
          float hv = rr[i]*(acc[nt][i] - mr[i]*Cv) + Bv;
          hw[(lq*4 + i)*136 + nt*16 + lr] = f2b(geluf(hv));
        }
      }
    }
    f32x4 a2[4];
    #pragma unroll
    for (int nt = 0; nt < 4; ++nt) a2[nt] = zero4;
    #pragma unroll
    for (int ks = 0; ks < 4; ++ks) {
      bf16x8 a = *(const bf16x8*)(hw + lr*136 + ks*32 + lq*8);
      #pragma unroll
      for (int nt = 0; nt < 4; ++nt)
        a2[nt] = __builtin_amdgcn_mfma_f32_16x16x32_bf16(a, f2[(nt*4 + ks)*64 + l], a2[nt], 0, 0, 0);
    }
    float ss[4] = {0.f,0.f,0.f,0.f}, qq[4] = {0.f,0.f,0.f,0.f};
    {
      unsigned short* s64p = (unsigned short*)(wsb + O_S64);
      #pragma unroll
      for (int nt = 0; nt < 4; ++nt) {
        float bv = sp2_b[nt*16 + lr];
        #pragma unroll
        for (int i = 0; i < 4; ++i) {
          unsigned short rb = f2b(a2[nt][i] + bv);
          s64p[(size_t)(srow + lq*4 + i)*64 + nt*16 + lr] = rb;
          float f = b2f(rb);
          ss[i] += f; qq[i] = fmaf(f, f, qq[i]);
        }
      }
    }
    #pragma unroll
    for (int i = 0; i < 4; ++i) {
      ss[i] += __shfl_xor(ss[i], 1, 64); ss[i] += __shfl_xor(ss[i], 2, 64);
      ss[i] += __shfl_xor(ss[i], 4, 64); ss[i] += __shfl_xor(ss[i], 8, 64);
      qq[i] += __shfl_xor(qq[i], 1, 64); qq[i] += __shfl_xor(qq[i], 2, 64);
      qq[i] += __shfl_xor(qq[i], 4, 64); qq[i] += __shfl_xor(qq[i], 8, 64);
    }
    if (lr == 0) {
      float* stat = (float*)(wsb + O_STAT);
      #pragma unroll
      for (int i = 0; i < 4; ++i) {
        size_t r = (size_t)srow + lq*4 + i;
        float2 o; o.x = ss[i]; o.y = qq[i];   // PARTIAL (finalized in k1_scan)
        *(float2*)(stat + r*2) = o;
      }
    }
    return;
  }

  // ============ xproj role (round-13 dual-tile) ============
  float (*ctile)[16][100] = (float(*)[16][100])smem;      // [4][16][100]
  float (*bsh)[96] = (float(*)[96])(smem + 25600);        // [7][96]
  const unsigned ctA = blockIdx.x*128u + wv*32u + lr;
  const unsigned ctB = ctA + 16u;
  const int lqh = lq >> 1, lql = lq & 1;

  if (tid < 168)
    ((float4*)bsh)[tid] = ((const float4*)(wsb + O_BIAST))[tid];
  __syncthreads();

  int eA[8], eB[8];
  {
    const int4* ip = (const int4*)(x_cat + (size_t)ctA*16);
    int4 v0 = ip[0], v1 = ip[1], v2 = ip[2], v3 = ip[3];
    eA[0] = lqh ? v0.y : v0.x;  eA[1] = lqh ? v0.w : v0.z;
    eA[2] = lqh ? v1.y : v1.x;  eA[3] = lqh ? v1.w : v1.z;
    eA[4] = lqh ? v2.y : v2.x;  eA[5] = lqh ? v2.w : v2.z;
    eA[6] = lqh ? v3.y : v3.x;  eA[7] = lqh ? v3.w : v3.z;
  }
  {
    const int4* ip = (const int4*)(x_cat + (size_t)ctB*16);
    int4 v0 = ip[0], v1 = ip[1], v2 = ip[2], v3 = ip[3];
    eB[0] = lqh ? v0.y : v0.x;  eB[1] = lqh ? v0.w : v0.z;
    eB[2] = lqh ? v1.y : v1.x;  eB[3] = lqh ? v1.w : v1.z;
    eB[4] = lqh ? v2.y : v2.x;  eB[5] = lqh ? v2.w : v2.z;
    eB[6] = lqh ? v3.y : v3.x;  eB[7] = lqh ? v3.w : v3.z;
  }
  const unsigned short* emb = (const unsigned short*)(wsb + O_EMB16);
  const bf16x8* xp2 = (const bf16x8*)(wsb + O_XP2FR);
  f32x4 accA[6], accB[6];
  #pragma unroll
  for (int nt = 0; nt < 6; ++nt) { accA[nt] = zero4; accB[nt] = zero4; }

  { // ks=0: x_num operands
    union { bf16x8 v; unsigned short u[8]; } auA, auB;
    {
      const float* xa = x_num + (size_t)ctA*32 + lq*8;
      const float* xb = x_num + (size_t)ctB*32 + lq*8;
      float fa[8], fb[8];
      *(float4*)&fa[0] = *(const float4*)xa;
      *(float4*)&fa[4] = *(const float4*)(xa + 4);
      *(float4*)&fb[0] = *(const float4*)xb;
      *(float4*)&fb[4] = *(const float4*)(xb + 4);
      #pragma unroll
      for (int j = 0; j < 8; ++j) { auA.u[j] = f2b(fa[j]); auB.u[j] = f2b(fb[j]); }
    }
    #pragma unroll
    for (int nt = 0; nt < 6; ++nt) {
      bf16x8 w = xp2[nt*64 + l];
      accA[nt] = __builtin_amdgcn_mfma_f32_16x16x32_bf16(auA.v, w, accA[nt], 0, 0, 0);
      accB[nt] = __builtin_amdgcn_mfma_f32_16x16x32_bf16(auB.v, w, accB[nt], 0, 0, 0);
    }
  }
  #pragma unroll
  for (int c2 = 0; c2 < 8; ++c2) {    // ks=1..8: raw emb operands
    bf16x8 aA = *(const bf16x8*)(emb + ((c2*2+lqh)*101 + eA[c2])*16 + lql*8);
    bf16x8 aB = *(const bf16x8*)(emb + ((c2*2+lqh)*101 + eB[c2])*16 + lql*8);
    #pragma unroll
    for (int nt = 0; nt < 6; ++nt) {
      bf16x8 w = xp2[((c2+1)*6+nt)*64 + l];
      accA[nt] = __builtin_amdgcn_mfma_f32_16x16x32_bf16(aA, w, accA[nt], 0, 0, 0);
      accB[nt] = __builtin_amdgcn_mfma_f32_16x16x32_bf16(aB, w, accB[nt], 0, 0, 0);
    }
  }

  // ---- tile A epilogue ----
  #pragma unroll
  for (int nt = 0; nt < 6; ++nt) {
    #pragma unroll
    for (int i = 0; i < 4; ++i)
      ctile[wv][lq*4 + i][nt*16 + lr] = accA[nt][i];
  }
  asm volatile("s_waitcnt lgkmcnt(0)" ::: "memory");
  __builtin_amdgcn_sched_barrier(0);
  {
    const unsigned t = ctA % 7u;
    float cv[24], bv[24];
    #pragma unroll
    for (int q = 0; q < 6; ++q) {
      *(float4*)&cv[q*4] = *(const float4*)&ctile[wv][lr][lq*24 + q*4];
      *(float4*)&bv[q*4] = *(const float4*)&bsh[t][lq*24 + q*4];
    }
    unsigned ow[12];
    float sm = 0.f, sq = 0.f;
    #pragma unroll
    for (int u = 0; u < 12; ++u) {
      unsigned short u0 = f2b(cv[2*u]   + bv[2*u]);
      unsigned short u1 = f2b(cv[2*u+1] + bv[2*u+1]);
      ow[u] = (unsigned)u0 | ((unsigned)u1 << 16);
      float f0 = b2f(u0), f1 = b2f(u1);
      sm += f0 + f1; sq = fmaf(f0, f0, fmaf(f1, f1, sq));
    }
    {
      uint4* xo = (uint4*)(xrow + (size_t)ctA*96 + lq*24);
      xo[0] = make_uint4(ow[0], ow[1], ow[2], ow[3]);
      xo[1] = make_uint4(ow[4], ow[5], ow[6], ow[7]);
      xo[2] = make_uint4(ow[8], ow[9], ow[10], ow[11]);
    }
    sm += __shfl_xor(sm, 16, 64); sm += __shfl_xor(sm, 32, 64);
    sq += __shfl_xor(sq, 16, 64); sq += __shfl_xor(sq, 32, 64);
    if (lq == 0) {
      float2 o; o.x = sm; o.y = sq;
      *(float2*)(xstat + (size_t)ctA*2) = o;
    }
  }
  asm volatile("s_waitcnt lgkmcnt(0)" ::: "memory");
  __builtin_amdgcn_sched_barrier(0);
  // ---- tile B epilogue ----
  #pragma unroll
  for (int nt = 0; nt < 6; ++nt) {
    #pragma unroll
    for (int i = 0; i < 4; ++i)
      ctile[wv][lq*4 + i][nt*16 + lr] = accB[nt][i];
  }
  asm volatile("s_waitcnt lgkmcnt(0)" ::: "memory");
  __builtin_amdgcn_sched_barrier(0);
  {
    const unsigned t = ctB % 7u;
    float cv[24], bv[24];
    #pragma unroll
    for (int q = 0; q < 6; ++q) {
      *(float4*)&cv[q*4] = *(const float4*)&ctile[wv][lr][lq*24 + q*4];
      *(float4*)&bv[q*4] = *(const float4*)&bsh[t][lq*24 + q*4];
    }
    unsigned ow[12];
    float sm = 0.f, sq = 0.f;
    #pragma unroll
    for (int u = 0; u < 12; ++u) {
      unsigned short u0 = f2b(cv[2*u]   + bv[2*u]);
      unsigned short u1 = f2b(cv[2*u+1] + bv[2*u+1]);
      ow[u] = (unsigned)u0 | ((unsigned)u1 << 16);
      float f0 = b2f(u0), f1 = b2f(u1);
      sm += f0 + f1; sq = fmaf(f0, f0, fmaf(f1, f1, sq));
    }
    {
      uint4* xo = (uint4*)(xrow + (size_t)ctB*96 + lq*24);
      xo[0] = make_uint4(ow[0], ow[1], ow[2], ow[3]);
      xo[1] = make_uint4(ow[4], ow[5], ow[6], ow[7]);
      xo[2] = make_uint4(ow[8], ow[9], ow[10], ow[11]);
    }
    sm += __shfl_xor(sm, 16, 64); sm += __shfl_xor(sm, 32, 64);
    sq += __shfl_xor(sq, 16, 64); sq += __shfl_xor(sq, 32, 64);
    if (lq == 0) {
      float2 o; o.x = sm; o.y = sq;
      *(float2*)(xstat + (size_t)ctB*2) = o;
    }
  }
}

// =================== K1: recurrence + FUSED HEADS (k2b absorbed) ===================
__global__ __launch_bounds__(512, 2) void k1_scan(
    const float* __restrict__ h0, const float* __restrict__ fc2_b,
    const float* __restrict__ hm2_b, const float* __restrict__ hq2_b,
    const float* __restrict__ hn2_b,
    const char* __restrict__ wsb, const unsigned short* __restrict__ xrow,
    const float* __restrict__ xstat, float* __restrict__ statg,
    float* __restrict__ out)
{
  extern __shared__ char smem[];
  unsigned short* zg = (unsigned short*)smem;              // [128][200] u16, 51200 B
  unsigned short* f1f = (unsigned short*)(smem + 51200);   // 73728 B
  unsigned short* f2f = (unsigned short*)(smem + 124928);  // 36864 B

  const int tid = threadIdx.x;
  const int wv = tid >> 6;
  const int l = tid & 63;
  const int lr = l & 15;
  const int lq = l >> 4;
  const int rowt = wv*16 + lr;

  { // stage frag tables to LDS
    const uint4* s1 = (const uint4*)(wsb + O_FC1FR);
    uint4* d1 = (uint4*)f1f;
    for (int o = tid; o < 4608; o += 512) d1[o] = s1[o];
    const uint4* s2 = (const uint4*)(wsb + O_FC2FR);
    uint4* d2 = (uint4*)f2f;
    for (int o = tid; o < 2304; o += 512) d2[o] = s2[o];
  }
  const bf16x8* f1v = (const bf16x8*)f1f;
  const bf16x8* f2v = (const bf16x8*)f2f;

  float C1[12], B1[12];
  {
    const float* fc1C = (const float*)(wsb + O_FC1C);
    const float* fc1BP = (const float*)(wsb + O_FC1BP);
    #pragma unroll
    for (int nt = 0; nt < 12; ++nt) { C1[nt] = fc1C[nt*16+lr]; B1[nt] = fc1BP[nt*16+lr]; }
  }
  float fb2[6];
  #pragma unroll
  for (int nt = 0; nt < 6; ++nt) fb2[nt] = fc2_b[nt*16+lr];

  float h[24], hs[24], hm[24];
  #pragma unroll
  for (int nt = 0; nt < 6; ++nt) {
    float v = h0[nt*16+lr];
    #pragma unroll
    for (int i = 0; i < 4; ++i) { h[nt*4+i] = v; hs[nt*4+i] = 0.f; hm[nt*4+i] = -3.4e38f; }
  }
  __syncthreads();

  const f32x4 zero4 = {0.f, 0.f, 0.f, 0.f};
  const size_t srow_q = (size_t)blockIdx.x*128 + wv*16;    // wave sample base

  for (int t = 0; t < 7; ++t) {
    // ---- (a) write h (bf16) to zg cols 0..95 + C-layout row stats ----
    float hsm[4] = {0.f,0.f,0.f,0.f}, hsq[4] = {0.f,0.f,0.f,0.f};
    #pragma unroll
    for (int nt = 0; nt < 6; ++nt) {
      #pragma unroll
      for (int i = 0; i < 4; ++i) {
        unsigned short hb = f2b(h[nt*4+i]);
        zg[(wv*16 + lq*4 + i)*200 + nt*16 + lr] = hb;
        float hf = b2f(hb);
        hsm[i] += hf; hsq[i] = fmaf(hf, hf, hsq[i]);
      }
    }
    #pragma unroll
    for (int i = 0; i < 4; ++i) {
      hsm[i] += __shfl_xor(hsm[i], 1, 64); hsm[i] += __shfl_xor(hsm[i], 2, 64);
      hsm[i] += __shfl_xor(hsm[i], 4, 64); hsm[i] += __shfl_xor(hsm[i], 8, 64);
      hsq[i] += __shfl_xor(hsq[i], 1, 64); hsq[i] += __shfl_xor(hsq[i], 2, 64);
      hsq[i] += __shfl_xor(hsq[i], 4, 64); hsq[i] += __shfl_xor(hsq[i], 8, 64);
    }
    // ---- (b) combine with precomputed x-stats ----
    float mr[4], rr[4];
    #pragma unroll
    for (int i = 0; i < 4; ++i) {
      const float2 xs = *(const float2*)(xstat + ((srow_q + lq*4 + i)*7 + t)*2);
      float m = (hsm[i] + xs.x) * (1.f/192.f);
      float var = (hsq[i] + xs.y) * (1.f/192.f) - m*m;
      mr[i] = m; rr[i] = rsqrtf(var + 1e-5f);
    }
    // ---- (c) fc1 GEMM: A = [h from LDS | x from global] ----
    bf16x8 ax[3];
    {
      const unsigned short* xp = xrow + ((srow_q + lr)*7 + t)*96;
      #pragma unroll
      for (int k3 = 0; k3 < 3; ++k3)
        ax[k3] = *(const bf16x8*)(xp + k3*32 + lq*8);
    }
    f32x4 acc[12];
    #pragma unroll
    for (int nt = 0; nt < 12; ++nt) acc[nt] = zero4;
    #pragma unroll
    for (int ks = 0; ks < 3; ++ks) {
      bf16x8 a = *(const bf16x8*)(zg + rowt*200 + ks*32 + lq*8);
      #pragma unroll
      for (int nt = 0; nt < 12; ++nt)
        acc[nt] = __builtin_amdgcn_mfma_f32_16x16x32_bf16(a, f1v[(nt*6+ks)*64 + l], acc[nt], 0, 0, 0);
    }
    #pragma unroll
    for (int k3 = 0; k3 < 3; ++k3) {
      #pragma unroll
      for (int nt = 0; nt < 12; ++nt)
        acc[nt] = __builtin_amdgcn_mfma_f32_16x16x32_bf16(ax[k3], f1v[(nt*6+k3+3)*64 + l], acc[nt], 0, 0, 0);
    }
    // ---- (d) LN-finish + gelu -> g (cols 0..191) ----
    #pragma unroll
    for (int nt = 0; nt < 12; ++nt) {
      #pragma unroll
      for (int i = 0; i < 4; ++i) {
        float hid = rr[i]*(acc[nt][i] - mr[i]*C1[nt]) + B1[nt];
        zg[(wv*16 + lq*4 + i)*200 + nt*16 + lr] = f2b(geluf(hid));
      }
    }
    // ---- (e) fc2 GEMM ----
    f32x4 a2[6];
    #pragma unroll
    for (int nt = 0; nt < 6; ++nt) a2[nt] = zero4;
    #pragma unroll
    for (int ks = 0; ks < 6; ++ks) {
      bf16x8 a = *(const bf16x8*)(zg + rowt*200 + ks*32 + lq*8);
      #pragma unroll
      for (int nt = 0; nt < 6; ++nt)
        a2[nt] = __builtin_amdgcn_mfma_f32_16x16x32_bf16(a, f2v[(nt*6+ks)*64 + l], a2[nt], 0, 0, 0);
    }
    // ---- (f) h update ----
    #pragma unroll
    for (int nt = 0; nt < 6; ++nt) {
      #pragma unroll
      for (int i = 0; i < 4; ++i) {
        int u = nt*4 + i;
        h[u] += a2[nt][i] + fb2[nt];
        hs[u] += h[u];
        hm[u] = fmaxf(hm[u], h[u]);
      }
    }
  }

  // ======== fused heads (replaces k2b) ========
  __syncthreads();   // t-loop LDS fully consumed; reuse smem as z-tile [128][360]
  unsigned short* zt = (unsigned short*)smem;
  float st[4] = {0.f,0.f,0.f,0.f}, qt[4] = {0.f,0.f,0.f,0.f};
  #pragma unroll
  for (int nt = 0; nt < 6; ++nt) {
    #pragma unroll
    for (int i = 0; i < 4; ++i) {
      int row = wv*16 + lq*4 + i;
      int c = nt*16 + lr;
      unsigned short b0 = f2b(h[nt*4+i]);
      unsigned short b1 = f2b(hs[nt*4+i]*(1.f/7.f));
      unsigned short b2v = f2b(hm[nt*4+i]);
      zt[row*360 + c] = b0;
      zt[row*360 + 96 + c] = b1;
      zt[row*360 + 192 + c] = b2v;
      float f0 = b2f(b0), f1 = b2f(b1), f2x = b2f(b2v);
      st[i] += f0 + f1 + f2x;
      qt[i] = fmaf(f0, f0, fmaf(f1, f1, fmaf(f2x, f2x, qt[i])));
    }
  }
  { // s64 -> zt cols 288..351 (wave-private rows)
    const unsigned short* s64p = (const unsigned short*)(wsb + O_S64);
    const uint4* sp = (const uint4*)(s64p + (srow_q + lr)*64 + lq*16);
    uint4 v0 = sp[0], v1 = sp[1];
    *(uint4*)(zt + (wv*16 + lr)*360 + 288 + lq*16) = v0;
    *(uint4*)(zt + (wv*16 + lr)*360 + 288 + lq*16 + 8) = v1;
  }
  // stats: reduce over lr (all lanes end with totals), add k1ab partials
  #pragma unroll
  for (int i = 0; i < 4; ++i) {
    st[i] += __shfl_xor(st[i], 1, 64); st[i] += __shfl_xor(st[i], 2, 64);
    st[i] += __shfl_xor(st[i], 4, 64); st[i] += __shfl_xor(st[i], 8, 64);
    qt[i] += __shfl_xor(qt[i], 1, 64); qt[i] += __shfl_xor(qt[i], 2, 64);
    qt[i] += __shfl_xor(qt[i], 4, 64); qt[i] += __shfl_xor(qt[i], 8, 64);
  }
  float mr[4], rr[4];
  #pragma unroll
  for (int i = 0; i < 4; ++i) {
    const float2 fs = *(const float2*)(statg + (srow_q + lq*4 + i)*2);
    float stot = fs.x + st[i], qtot = fs.y + qt[i];
    float m = stot*(1.f/352.f);
    float var = qtot*(1.f/352.f) - m*m;
    mr[i] = m; rr[i] = rsqrtf(var + 1e-5f);
  }
  // head GEMM: M=16 (own rows), 30 nt x 11 ks; B-frags streamed from L2
  const bf16x8* hv = (const bf16x8*)(wsb + O_HDFR);
  const float* hdC = (const float*)(wsb + O_HDC);
  const float* hdB = (const float*)(wsb + O_HDBP);
  const float* w2c = (const float*)(wsb + O_W2C);
  float p0[4] = {0.f,0.f,0.f,0.f}, p1[4] = {0.f,0.f,0.f,0.f}, p2[4] = {0.f,0.f,0.f,0.f};
  #pragma unroll
  for (int nt = 0; nt < 30; ++nt) {
    const int col = nt*16 + lr;
    const float Cv = hdC[col], Bv = hdB[col], w2v = w2c[col];
    f32x4 a0 = zero4;
    #pragma unroll
    for (int ks = 0; ks < 11; ++ks) {
      bf16x8 b = hv[(nt*11 + ks)*64 + l];
      bf16x8 a = *(const bf16x8*)(zt + (wv*16 + lr)*360 + ks*32 + lq*8);
      a0 = __builtin_amdgcn_mfma_f32_16x16x32_bf16(a, b, a0, 0, 0, 0);
    }
    #pragma unroll
    for (int i = 0; i < 4; ++i) {
      float g = geluf(rr[i]*(a0[i] - mr[i]*Cv) + Bv) * w2v;
      if (nt < 12) p0[i] += g; else if (nt < 24) p1[i] += g; else p2[i] += g;
    }
  }
  #pragma unroll
  for (int i = 0; i < 4; ++i) {
    p0[i] += __shfl_xor(p0[i], 1, 64); p0[i] += __shfl_xor(p0[i], 2, 64);
    p0[i] += __shfl_xor(p0[i], 4, 64); p0[i] += __shfl_xor(p0[i], 8, 64);
    p1[i] += __shfl_xor(p1[i], 1, 64); p1[i] += __shfl_xor(p1[i], 2, 64);
    p1[i] += __shfl_xor(p1[i], 4, 64); p1[i] += __shfl_xor(p1[i], 8, 64);
    p2[i] += __shfl_xor(p2[i], 1, 64); p2[i] += __shfl_xor(p2[i], 2, 64);
    p2[i] += __shfl_xor(p2[i], 4, 64); p2[i] += __shfl_xor(p2[i], 8, 64);
  }
  if (lr == 0) {
    const float* baseb = (const float*)(wsb + O_BASE);
    const float hmb = hm2_b[0], hqb = hq2_b[0], hnb = hn2_b[0];
    #pragma unroll
    for (int i = 0; i < 4; ++i) {
      size_t r = srow_q + lq*4 + i;
      float bs = baseb[r];
      out[r] = bs + hmb + p0[i];
      out[NB + r] = bs + hqb + p1[i];
      out[2*NB + r] = hnb + p2[i];
    }
  }
}

extern "C" void kernel_launch(void* const* d_in, const int* in_sizes, int n_in,
                              void* d_out, int out_size, void* d_ws, size_t ws_size,
                              hipStream_t stream) {
  (void)in_sizes; (void)n_in; (void)out_size; (void)ws_size;
  const float* x_num    = (const float*)d_in[0];
  const float* x_static = (const float*)d_in[1];
  const int*   x_cat    = (const int*)  d_in[2];
  const float* cat_emb  = (const float*)d_in[3];
  const float* day_emb  = (const float*)d_in[4];
  const float* xproj_w  = (const float*)d_in[5];
  const float* xproj_b  = (const float*)d_in[6];
  const float* h0       = (const float*)d_in[7];
  const float* bln_g    = (const float*)d_in[8];
  const float* bln_b    = (const float*)d_in[9];
  const float* fc1_w    = (const float*)d_in[10];
  const float* fc1_b    = (const float*)d_in[11];
  const float* fc2_w    = (const float*)d_in[12];
  const float* fc2_b    = (const float*)d_in[13];
  const float* spln_g   = (const float*)d_in[14];
  const float* spln_b   = (const float*)d_in[15];
  const float* sp1_w    = (const float*)d_in[16];
  const float* sp1_b    = (const float*)d_in[17];
  const float* sp2_w    = (const float*)d_in[18];
  const float* sp2_b    = (const float*)d_in[19];
  const float* base_w   = (const float*)d_in[20];
  const float* base_b   = (const float*)d_in[21];
  const float* hln_g    = (const float*)d_in[22];
  const float* hln_b    = (const float*)d_in[23];
  const float* hm1_w    = (const float*)d_in[24];
  const float* hm1_b    = (const float*)d_in[25];
  const float* hm2_w    = (const float*)d_in[26];
  const float* hm2_b    = (const float*)d_in[27];
  const float* hq1_w    = (const float*)d_in[28];
  const float* hq1_b    = (const float*)d_in[29];
  const float* hq2_w    = (const float*)d_in[30];
  const float* hq2_b    = (const float*)d_in[31];
  const float* hn1_w    = (const float*)d_in[32];
  const float* hn1_b    = (const float*)d_in[33];
  const float* hn2_w    = (const float*)d_in[34];
  const float* hn2_b    = (const float*)d_in[35];

  char* wsb = (char*)d_ws;
  unsigned short* xrow = (unsigned short*)(wsb + O_XROW);
  float* xstat = (float*)(wsb + O_XSTAT);
  float* statg = (float*)(wsb + O_STAT);
  float* out = (float*)d_out;

  k0_pre<<<589, 512, 0, stream>>>(cat_emb, day_emb, xproj_w, xproj_b,
      bln_g, bln_b, fc1_w, fc1_b, fc2_w, spln_g, spln_b, sp1_w, sp1_b, sp2_w,
      hln_g, hln_b, hm1_w, hm1_b, hq1_w, hq1_b, hn1_w, hn1_b,
      hm2_w, hq2_w, hn2_w, wsb);
  k1ab<<<4608, 256, 0, stream>>>(x_num, x_cat, x_static, sp2_b, base_w, base_b,
      wsb, xrow, xstat);
  k1_scan<<<512, 512, 161792, stream>>>(h0, fc2_b, hm2_b, hq2_b, hn2_b,
      wsb, xrow, xstat, statg, out);
}

// Round 17
// 278.508 us; speedup vs baseline: 1.4246x; 1.4246x over previous
//
#include <hip/hip_runtime.h>
#include <math.h>

#define NB 65536

typedef __attribute__((ext_vector_type(8))) short bf16x8;
typedef __attribute__((ext_vector_type(4))) float f32x4;

// ---- ws byte offsets ----
#define O_BIAST  0         // f32 [7][96]                 2688
#define O_FC1C   4096      // f32 [192]
#define O_FC1BP  8192      // f32 [192]
#define O_FC1FR  12288     // u16 [72][64][8]   73728  -> 86016
#define O_FC2FR  86016     // u16 [36][64][8]   36864  -> 122880
#define O_HDFR   122880    // u16 [330][64][8]  337920 -> 460800
#define O_HDC    460800    // f32 [480]
#define O_HDBP   462848    // f32 [480]
#define O_W2C    464896    // f32 [480]
#define O_SPC    466944    // f32 [128]
#define O_SPB    467968    // f32 [128]
#define O_SP1FR  468992    // u16 [16][64][8]   16384  -> 485376
#define O_SP2FR  485376    // u16 [16][64][8]   16384  -> 501760
#define O_XP2FR  501760    // u16 [54][64][8]   55296  -> 557056
#define O_EMB16  557056    // u16 [16][101][16] 51712  -> 608768
#define O_FEAT   608768    // u16 [65536][288]  37748736 -> 38357504
#define O_S64    38357504  // u16 [65536][64]   8388608  -> 46746112
#define O_STAT   46746112  // f32 [65536][2]    524288   -> 47270400
#define O_BASE   47270400  // f32 [65536]       262144   -> 47532544
#define O_XROW   47532544  // u16 [458752][96]  88080384 -> 135612928
#define O_XSTAT  135612928 // f32 [458752][2]   3670016  -> 139282944

__device__ __forceinline__ unsigned short f2b(float x) {
  unsigned int u = __float_as_uint(x);
  u += 0x7fffu + ((u >> 16) & 1u);   // RNE bf16
  return (unsigned short)(u >> 16);
}
__device__ __forceinline__ float b2f(unsigned short u) {
  return __uint_as_float(((unsigned)u) << 16);
}
// tanh-form GELU, branch-free (round-9 proven: absmax unchanged)
__device__ __forceinline__ float geluf(float x) {
  float z = x * x;
  float e = __builtin_amdgcn_exp2f(-x * (2.3022137f + 0.10294456f * z));
  return x * __builtin_amdgcn_rcpf(1.0f + e);
}

// head LN-fold, 4-way k-split: part covers cols part*120..+119, 4 lanes/col
__device__ __forceinline__ void head_fold_part(
    int part, int tid,
    const float* __restrict__ hln_g, const float* __restrict__ hln_b,
    const float* __restrict__ hm1_w, const float* __restrict__ hm1_b,
    const float* __restrict__ hq1_w, const float* __restrict__ hq1_b,
    const float* __restrict__ hn1_w, const float* __restrict__ hn1_b,
    const float* __restrict__ hm2_w, const float* __restrict__ hq2_w,
    const float* __restrict__ hn2_w, char* __restrict__ wsb)
{
  if (tid >= 480) return;
  const int gcol = part*120 + (tid >> 2);
  const int ksl = tid & 3;
  float C = 0.f, Bp = 0.f;
  for (int j = 0; j < 88; ++j) {
    int k = ksl*88 + j;
    float w;
    if (gcol < 192) w = hm1_w[k*192 + gcol];
    else if (gcol < 384) w = hq1_w[k*192 + (gcol-192)];
    else w = hn1_w[k*96 + (gcol-384)];
    C = fmaf(hln_g[k], w, C);
    Bp = fmaf(hln_b[k], w, Bp);
  }
  C += __shfl_xor(C, 1, 64); C += __shfl_xor(C, 2, 64);
  Bp += __shfl_xor(Bp, 1, 64); Bp += __shfl_xor(Bp, 2, 64);
  if (ksl == 0) {
    float b0, w2;
    if (gcol < 192) { b0 = hm1_b[gcol]; w2 = hm2_w[gcol]; }
    else if (gcol < 384) { b0 = hq1_b[gcol-192]; w2 = hq2_w[gcol-192]; }
    else { b0 = hn1_b[gcol-384]; w2 = hn2_w[gcol-384]; }
    ((float*)(wsb + O_HDC))[gcol] = C;
    ((float*)(wsb + O_HDBP))[gcol] = Bp + b0;
    ((float*)(wsb + O_W2C))[gcol] = w2;
  }
}

// =================== K0: fold + frag-pack all weights ===================
__global__ void k0_pre(
    const float* __restrict__ cat_emb, const float* __restrict__ day_emb,
    const float* __restrict__ xproj_w, const float* __restrict__ xproj_b,
    const float* __restrict__ bln_g, const float* __restrict__ bln_b,
    const float* __restrict__ fc1_w, const float* __restrict__ fc1_b,
    const float* __restrict__ fc2_w,
    const float* __restrict__ spln_g, const float* __restrict__ spln_b,
    const float* __restrict__ sp1_w, const float* __restrict__ sp1_b,
    const float* __restrict__ sp2_w,
    const float* __restrict__ hln_g, const float* __restrict__ hln_b,
    const float* __restrict__ hm1_w, const float* __restrict__ hm1_b,
    const float* __restrict__ hq1_w, const float* __restrict__ hq1_b,
    const float* __restrict__ hn1_w, const float* __restrict__ hn1_b,
    const float* __restrict__ hm2_w, const float* __restrict__ hq2_w,
    const float* __restrict__ hn2_w,
    char* __restrict__ wsb)
{
  const int b = blockIdx.x, tid = threadIdx.x;
  if (b < 7) {                        // per-t bias (xproj_b + day part)
    if (tid < 96) {
      int t = b;
      float acc = xproj_b[tid];
      #pragma unroll
      for (int d = 0; d < 8; ++d)
        acc = fmaf(day_emb[(1+t)*8 + d], xproj_w[(288+d)*96 + tid], acc);
      ((float*)(wsb + O_BIAST))[t*96 + tid] = acc;
    }
  } else if (b < 9) {                 // fc1 LN-fold C / B' (4-way k-split)
    if (tid < 384) {
      int col = (b-7)*96 + (tid >> 2);
      int ksl = tid & 3;
      float C = 0.f, Bp = 0.f;
      for (int j = 0; j < 48; ++j) {
        int k = ksl*48 + j;
        float w = fc1_w[k*192 + col];
        C = fmaf(bln_g[k], w, C);
        Bp = fmaf(bln_b[k], w, Bp);
      }
      C += __shfl_xor(C, 1, 64); C += __shfl_xor(C, 2, 64);
      Bp += __shfl_xor(Bp, 1, 64); Bp += __shfl_xor(Bp, 2, 64);
      if (ksl == 0) {
        ((float*)(wsb + O_FC1C))[col] = C;
        ((float*)(wsb + O_FC1BP))[col] = Bp + fc1_b[col];
      }
    }
  } else if (b < 81) {                // fc1 frags [nt(12)][ks(6)]
    int seg = b - 9, nt = seg / 6, ks = seg - nt*6;
    int ln = tid >> 3, j = tid & 7;
    int k = ks*32 + (ln>>4)*8 + j, col = nt*16 + (ln&15);
    ((unsigned short*)(wsb + O_FC1FR))[(seg*64 + ln)*8 + j] = f2b(bln_g[k]*fc1_w[k*192 + col]);
  } else if (b < 117) {               // fc2 frags [nt(6)][ks(6)]
    int seg = b - 81, nt = seg / 6, ks = seg - nt*6;
    int ln = tid >> 3, j = tid & 7;
    int k = ks*32 + (ln>>4)*8 + j, col = nt*16 + (ln&15);
    ((unsigned short*)(wsb + O_FC2FR))[(seg*64 + ln)*8 + j] = f2b(fc2_w[k*96 + col]);
  } else if (b < 447) {               // head frags [nt(30)][ks(11)]
    int seg = b - 117, nt = seg / 11, ks = seg - nt*11;
    int ln = tid >> 3, j = tid & 7;
    int k = ks*32 + (ln>>4)*8 + j, gcol = nt*16 + (ln&15);
    float w;
    if (gcol < 192) w = hm1_w[k*192 + gcol];
    else if (gcol < 384) w = hq1_w[k*192 + (gcol-192)];
    else w = hn1_w[k*96 + (gcol-384)];
    ((unsigned short*)(wsb + O_HDFR))[(seg*64 + ln)*8 + j] = f2b(hln_g[k]*w);
  } else if (b < 448) {               // head fold part 0 (cols 0..119)
    head_fold_part(0, tid, hln_g, hln_b, hm1_w, hm1_b, hq1_w, hq1_b,
                   hn1_w, hn1_b, hm2_w, hq2_w, hn2_w, wsb);
  } else if (b < 449) {               // sp1 LN-fold (C from bf16-rounded weights)
    if (tid < 128) {
      int col = tid;
      float C = 0.f, Bp = sp1_b[col];
      for (int k = 0; k < 64; ++k) {
        float w = sp1_w[k*128 + col];
        C += b2f(f2b(spln_g[k]*w));
        Bp = fmaf(spln_b[k], w, Bp);
      }
      ((float*)(wsb + O_SPC))[col] = C;
      ((float*)(wsb + O_SPB))[col] = Bp;
    }
  } else if (b < 465) {               // sp1 frags [nt(8)][ks(2)]
    int seg = b - 449;
    int ln = tid >> 3, j = tid & 7;
    int nt = seg >> 1, ks = seg & 1;
    int k = ks*32 + (ln>>4)*8 + j, col = nt*16 + (ln&15);
    ((unsigned short*)(wsb + O_SP1FR))[(seg*64 + ln)*8 + j] = f2b(spln_g[k]*sp1_w[k*128 + col]);
  } else if (b < 481) {               // sp2 frags [nt(4)][ks(4)]
    int seg = b - 465;
    int ln = tid >> 3, j = tid & 7;
    int ks = seg & 3;
    int k = ks*32 + (ln>>4)*8 + j, col = (seg >> 2)*16 + (ln&15);
    ((unsigned short*)(wsb + O_SP2FR))[(seg*64 + ln)*8 + j] = f2b(sp2_w[k*64 + col]);
  } else if (b < 535) {               // xproj K=288 frags [ks(9)][nt(6)]
    int seg = b - 481, ks = seg / 6, nt = seg - ks*6;
    int ln = tid >> 3, j = tid & 7;
    int k = ks*32 + (ln>>4)*8 + j, col = nt*16 + (ln&15);
    ((unsigned short*)(wsb + O_XP2FR))[(seg*64 + ln)*8 + j] = f2b(xproj_w[k*96 + col]);
  } else if (b < 586) {               // raw emb table -> bf16 [16][101][16]
    int i = (b - 535)*512 + tid;
    if (i < 25856)
      ((unsigned short*)(wsb + O_EMB16))[i] = f2b(cat_emb[i]);
  } else {                            // head fold parts 1..3 (b = 586..588)
    head_fold_part(b - 585, tid, hln_g, hln_b, hm1_w, hm1_b, hq1_w, hq1_b,
                   hn1_w, hn1_b, hm2_w, hq2_w, hn2_w, wsb);
  }
}

// =================== K1ab: fused x-projection + static MLP ===================
// blocks 0..3583: dual-tile xproj (round-13 proven).
// blocks 3584..4607: static MLP, 4 waves x 16 samples; frags streamed from L2;
//   writes s64/base + PARTIAL z-stats (finalized in k1_scan — commutative add).
__global__ __launch_bounds__(256) void k1ab(
    const float* __restrict__ x_num, const int* __restrict__ x_cat,
    const float* __restrict__ x_static, const float* __restrict__ sp2_b,
    const float* __restrict__ base_w, const float* __restrict__ base_b,
    char* __restrict__ wsb, unsigned short* __restrict__ xrow,
    float* __restrict__ xstat)
{
  __shared__ char smem[28288];   // k1a: ctile(25600)+bsh(2688); k1b: hid(17408)
  const int tid = threadIdx.x;
  const int wv = tid >> 6, l = tid & 63, lr = l & 15, lq = l >> 4;
  const f32x4 zero4 = {0.f, 0.f, 0.f, 0.f};

  if (blockIdx.x >= 3584) {
    // ============ static-MLP role ============
    unsigned short* hid = (unsigned short*)smem;
    const int srow = (blockIdx.x - 3584)*64 + wv*16;

    float x0f[8], x1f[8];
    {
      const float* xr = x_static + (size_t)(srow + lr)*64;
      *(float4*)&x0f[0] = *(const float4*)(xr + lq*8);
      *(float4*)&x0f[4] = *(const float4*)(xr + lq*8 + 4);
      *(float4*)&x1f[0] = *(const float4*)(xr + 32 + lq*8);
      *(float4*)&x1f[4] = *(const float4*)(xr + 32 + lq*8 + 4);
    }
    float sm = 0.f, sq = 0.f, bp = 0.f;
    #pragma unroll
    for (int j = 0; j < 8; ++j) {
      sm += x0f[j] + x1f[j];
      sq = fmaf(x0f[j], x0f[j], fmaf(x1f[j], x1f[j], sq));
      bp = fmaf(x0f[j], base_w[lq*8 + j], fmaf(x1f[j], base_w[32 + lq*8 + j], bp));
    }
    sm += __shfl_xor(sm, 16, 64); sm += __shfl_xor(sm, 32, 64);
    sq += __shfl_xor(sq, 16, 64); sq += __shfl_xor(sq, 32, 64);
    bp += __shfl_xor(bp, 16, 64); bp += __shfl_xor(bp, 32, 64);
    if (lq == 0) ((float*)(wsb + O_BASE))[srow + lr] = bp + base_b[0];
    const float ms = sm*(1.f/64.f);
    const float rs = rsqrtf(sq*(1.f/64.f) - ms*ms + 1e-5f);
    float mr[4], rr[4];
    #pragma unroll
    for (int i = 0; i < 4; ++i) {
      mr[i] = __shfl(ms, lq*4 + i, 16);
      rr[i] = __shfl(rs, lq*4 + i, 16);
    }
    union { bf16x8 v; unsigned short u[8]; } ua0, ua1;
    #pragma unroll
    for (int j = 0; j < 8; ++j) { ua0.u[j] = f2b(x0f[j]); ua1.u[j] = f2b(x1f[j]); }

    const bf16x8* f1 = (const bf16x8*)(wsb + O_SP1FR);
    const bf16x8* f2 = (const bf16x8*)(wsb + O_SP2FR);
    unsigned short* hw = hid + wv*2176;

    f32x4 acc[8];
    #pragma unroll
    for (int nt = 0; nt < 8; ++nt) acc[nt] = zero4;
    #pragma unroll
    for (int nt = 0; nt < 8; ++nt) {
      acc[nt] = __builtin_amdgcn_mfma_f32_16x16x32_bf16(ua0.v, f1[(nt*2 + 0)*64 + l], acc[nt], 0, 0, 0);
      acc[nt] = __builtin_amdgcn_mfma_f32_16x16x32_bf16(ua1.v, f1[(nt*2 + 1)*64 + l], acc[nt], 0, 0, 0);
    }
    {
      const float* spC = (const float*)(wsb + O_SPC);
      const float* spB = (const float*)(wsb + O_SPB);
      #pragma unroll
      for (int nt = 0; nt < 8; ++nt) {
        float Cv = spC[nt*16 + lr], Bv = spB[nt*16 + lr];
        #pragma unroll
        for (int i = 0; i < 4; ++i) {
          float hv = rr[i]*(acc[nt][i] - mr[i]*Cv) + Bv;
          hw[(lq*4 + i)*136 + nt*16 + lr] = f2b(geluf(hv));
        }
      }
    }
    f32x4 a2[4];
    #pragma unroll
    for (int nt = 0; nt < 4; ++nt) a2[nt] = zero4;
    #pragma unroll
    for (int ks = 0; ks < 4; ++ks) {
      bf16x8 a = *(const bf16x8*)(hw + lr*136 + ks*32 + lq*8);
      #pragma unroll
      for (int nt = 0; nt < 4; ++nt)
        a2[nt] = __builtin_amdgcn_mfma_f32_16x16x32_bf16(a, f2[(nt*4 + ks)*64 + l], a2[nt], 0, 0, 0);
    }
    float ss[4] = {0.f,0.f,0.f,0.f}, qq[4] = {0.f,0.f,0.f,0.f};
    {
      unsigned short* s64p = (unsigned short*)(wsb + O_S64);
      #pragma unroll
      for (int nt = 0; nt < 4; ++nt) {
        float bv = sp2_b[nt*16 + lr];
        #pragma unroll
        for (int i = 0; i < 4; ++i) {
          unsigned short rb = f2b(a2[nt][i] + bv);
          s64p[(size_t)(srow + lq*4 + i)*64 + nt*16 + lr] = rb;
          float f = b2f(rb);
          ss[i] += f; qq[i] = fmaf(f, f, qq[i]);
        }
      }
    }
    #pragma unroll
    for (int i = 0; i < 4; ++i) {
      ss[i] += __shfl_xor(ss[i], 1, 64); ss[i] += __shfl_xor(ss[i], 2, 64);
      ss[i] += __shfl_xor(ss[i], 4, 64); ss[i] += __shfl_xor(ss[i], 8, 64);
      qq[i] += __shfl_xor(qq[i], 1, 64); qq[i] += __shfl_xor(qq[i], 2, 64);
      qq[i] += __shfl_xor(qq[i], 4, 64); qq[i] += __shfl_xor(qq[i], 8, 64);
    }
    if (lr == 0) {
      float* stat = (float*)(wsb + O_STAT);
      #pragma unroll
      for (int i = 0; i < 4; ++i) {
        size_t r = (size_t)srow + lq*4 + i;
        float2 o; o.x = ss[i]; o.y = qq[i];   // PARTIAL (finalized in k1_scan)
        *(float2*)(stat + r*2) = o;
      }
    }
    return;
  }

  // ============ xproj role (round-13 dual-tile) ============
  float (*ctile)[16][100] = (float(*)[16][100])smem;      // [4][16][100]
  float (*bsh)[96] = (float(*)[96])(smem + 25600);        // [7][96]
  const unsigned ctA = blockIdx.x*128u + wv*32u + lr;
  const unsigned ctB = ctA + 16u;
  const int lqh = lq >> 1, lql = lq & 1;

  if (tid < 168)
    ((float4*)bsh)[tid] = ((const float4*)(wsb + O_BIAST))[tid];
  __syncthreads();

  int eA[8], eB[8];
  {
    const int4* ip = (const int4*)(x_cat + (size_t)ctA*16);
    int4 v0 = ip[0], v1 = ip[1], v2 = ip[2], v3 = ip[3];
    eA[0] = lqh ? v0.y : v0.x;  eA[1] = lqh ? v0.w : v0.z;
    eA[2] = lqh ? v1.y : v1.x;  eA[3] = lqh ? v1.w : v1.z;
    eA[4] = lqh ? v2.y : v2.x;  eA[5] = lqh ? v2.w : v2.z;
    eA[6] = lqh ? v3.y : v3.x;  eA[7] = lqh ? v3.w : v3.z;
  }
  {
    const int4* ip = (const int4*)(x_cat + (size_t)ctB*16);
    int4 v0 = ip[0], v1 = ip[1], v2 = ip[2], v3 = ip[3];
    eB[0] = lqh ? v0.y : v0.x;  eB[1] = lqh ? v0.w : v0.z;
    eB[2] = lqh ? v1.y : v1.x;  eB[3] = lqh ? v1.w : v1.z;
    eB[4] = lqh ? v2.y : v2.x;  eB[5] = lqh ? v2.w : v2.z;
    eB[6] = lqh ? v3.y : v3.x;  eB[7] = lqh ? v3.w : v3.z;
  }
  const unsigned short* emb = (const unsigned short*)(wsb + O_EMB16);
  const bf16x8* xp2 = (const bf16x8*)(wsb + O_XP2FR);
  f32x4 accA[6], accB[6];
  #pragma unroll
  for (int nt = 0; nt < 6; ++nt) { accA[nt] = zero4; accB[nt] = zero4; }

  { // ks=0: x_num operands
    union { bf16x8 v; unsigned short u[8]; } auA, auB;
    {
      const float* xa = x_num + (size_t)ctA*32 + lq*8;
      const float* xb = x_num + (size_t)ctB*32 + lq*8;
      float fa[8], fb[8];
      *(float4*)&fa[0] = *(const float4*)xa;
      *(float4*)&fa[4] = *(const float4*)(xa + 4);
      *(float4*)&fb[0] = *(const float4*)xb;
      *(float4*)&fb[4] = *(const float4*)(xb + 4);
      #pragma unroll
      for (int j = 0; j < 8; ++j) { auA.u[j] = f2b(fa[j]); auB.u[j] = f2b(fb[j]); }
    }
    #pragma unroll
    for (int nt = 0; nt < 6; ++nt) {
      bf16x8 w = xp2[nt*64 + l];
      accA[nt] = __builtin_amdgcn_mfma_f32_16x16x32_bf16(auA.v, w, accA[nt], 0, 0, 0);
      accB[nt] = __builtin_amdgcn_mfma_f32_16x16x32_bf16(auB.v, w, accB[nt], 0, 0, 0);
    }
  }
  #pragma unroll
  for (int c2 = 0; c2 < 8; ++c2) {    // ks=1..8: raw emb operands
    bf16x8 aA = *(const bf16x8*)(emb + ((c2*2+lqh)*101 + eA[c2])*16 + lql*8);
    bf16x8 aB = *(const bf16x8*)(emb + ((c2*2+lqh)*101 + eB[c2])*16 + lql*8);
    #pragma unroll
    for (int nt = 0; nt < 6; ++nt) {
      bf16x8 w = xp2[((c2+1)*6+nt)*64 + l];
      accA[nt] = __builtin_amdgcn_mfma_f32_16x16x32_bf16(aA, w, accA[nt], 0, 0, 0);
      accB[nt] = __builtin_amdgcn_mfma_f32_16x16x32_bf16(aB, w, accB[nt], 0, 0, 0);
    }
  }

  // ---- tile A epilogue ----
  #pragma unroll
  for (int nt = 0; nt < 6; ++nt) {
    #pragma unroll
    for (int i = 0; i < 4; ++i)
      ctile[wv][lq*4 + i][nt*16 + lr] = accA[nt][i];
  }
  asm volatile("s_waitcnt lgkmcnt(0)" ::: "memory");
  __builtin_amdgcn_sched_barrier(0);
  {
    const unsigned t = ctA % 7u;
    float cv[24], bv[24];
    #pragma unroll
    for (int q = 0; q < 6; ++q) {
      *(float4*)&cv[q*4] = *(const float4*)&ctile[wv][lr][lq*24 + q*4];
      *(float4*)&bv[q*4] = *(const float4*)&bsh[t][lq*24 + q*4];
    }
    unsigned ow[12];
    float sm = 0.f, sq = 0.f;
    #pragma unroll
    for (int u = 0; u < 12; ++u) {
      unsigned short u0 = f2b(cv[2*u]   + bv[2*u]);
      unsigned short u1 = f2b(cv[2*u+1] + bv[2*u+1]);
      ow[u] = (unsigned)u0 | ((unsigned)u1 << 16);
      float f0 = b2f(u0), f1 = b2f(u1);
      sm += f0 + f1; sq = fmaf(f0, f0, fmaf(f1, f1, sq));
    }
    {
      uint4* xo = (uint4*)(xrow + (size_t)ctA*96 + lq*24);
      xo[0] = make_uint4(ow[0], ow[1], ow[2], ow[3]);
      xo[1] = make_uint4(ow[4], ow[5], ow[6], ow[7]);
      xo[2] = make_uint4(ow[8], ow[9], ow[10], ow[11]);
    }
    sm += __shfl_xor(sm, 16, 64); sm += __shfl_xor(sm, 32, 64);
    sq += __shfl_xor(sq, 16, 64); sq += __shfl_xor(sq, 32, 64);
    if (lq == 0) {
      float2 o; o.x = sm; o.y = sq;
      *(float2*)(xstat + (size_t)ctA*2) = o;
    }
  }
  asm volatile("s_waitcnt lgkmcnt(0)" ::: "memory");
  __builtin_amdgcn_sched_barrier(0);
  // ---- tile B epilogue ----
  #pragma unroll
  for (int nt = 0; nt < 6; ++nt) {
    #pragma unroll
    for (int i = 0; i < 4; ++i)
      ctile[wv][lq*4 + i][nt*16 + lr] = accB[nt][i];
  }
  asm volatile("s_waitcnt lgkmcnt(0)" ::: "memory");
  __builtin_amdgcn_sched_barrier(0);
  {
    const unsigned t = ctB % 7u;
    float cv[24], bv[24];
    #pragma unroll
    for (int q = 0; q < 6; ++q) {
      *(float4*)&cv[q*4] = *(const float4*)&ctile[wv][lr][lq*24 + q*4];
      *(float4*)&bv[q*4] = *(const float4*)&bsh[t][lq*24 + q*4];
    }
    unsigned ow[12];
    float sm = 0.f, sq = 0.f;
    #pragma unroll
    for (int u = 0; u < 12; ++u) {
      unsigned short u0 = f2b(cv[2*u]   + bv[2*u]);
      unsigned short u1 = f2b(cv[2*u+1] + bv[2*u+1]);
      ow[u] = (unsigned)u0 | ((unsigned)u1 << 16);
      float f0 = b2f(u0), f1 = b2f(u1);
      sm += f0 + f1; sq = fmaf(f0, f0, fmaf(f1, f1, sq));
    }
    {
      uint4* xo = (uint4*)(xrow + (size_t)ctB*96 + lq*24);
      xo[0] = make_uint4(ow[0], ow[1], ow[2], ow[3]);
      xo[1] = make_uint4(ow[4], ow[5], ow[6], ow[7]);
      xo[2] = make_uint4(ow[8], ow[9], ow[10], ow[11]);
    }
    sm += __shfl_xor(sm, 16, 64); sm += __shfl_xor(sm, 32, 64);
    sq += __shfl_xor(sq, 16, 64); sq += __shfl_xor(sq, 32, 64);
    if (lq == 0) {
      float2 o; o.x = sm; o.y = sq;
      *(float2*)(xstat + (size_t)ctB*2) = o;
    }
  }
}

// =================== K1: 7-step MFMA recurrence (round-9 proven) + stat finalize ===================
__global__ __launch_bounds__(512, 2) void k1_scan(
    const float* __restrict__ h0, const float* __restrict__ fc2_b,
    const char* __restrict__ wsb, const unsigned short* __restrict__ xrow,
    const float* __restrict__ xstat, unsigned short* __restrict__ feat,
    float* __restrict__ statg)
{
  extern __shared__ char smem[];
  unsigned short* zg = (unsigned short*)smem;              // [128][200] u16, 51200 B
  unsigned short* f1f = (unsigned short*)(smem + 51200);   // 73728 B
  unsigned short* f2f = (unsigned short*)(smem + 124928);  // 36864 B

  const int tid = threadIdx.x;
  const int wv = tid >> 6;
  const int l = tid & 63;
  const int lr = l & 15;
  const int lq = l >> 4;
  const int rowt = wv*16 + lr;

  { // stage frag tables to LDS
    const uint4* s1 = (const uint4*)(wsb + O_FC1FR);
    uint4* d1 = (uint4*)f1f;
    for (int o = tid; o < 4608; o += 512) d1[o] = s1[o];
    const uint4* s2 = (const uint4*)(wsb + O_FC2FR);
    uint4* d2 = (uint4*)f2f;
    for (int o = tid; o < 2304; o += 512) d2[o] = s2[o];
  }
  const bf16x8* f1v = (const bf16x8*)f1f;
  const bf16x8* f2v = (const bf16x8*)f2f;

  float C1[12], B1[12];
  {
    const float* fc1C = (const float*)(wsb + O_FC1C);
    const float* fc1BP = (const float*)(wsb + O_FC1BP);
    #pragma unroll
    for (int nt = 0; nt < 12; ++nt) { C1[nt] = fc1C[nt*16+lr]; B1[nt] = fc1BP[nt*16+lr]; }
  }
  float fb2[6];
  #pragma unroll
  for (int nt = 0; nt < 6; ++nt) fb2[nt] = fc2_b[nt*16+lr];

  float h[24], hs[24], hm[24];
  #pragma unroll
  for (int nt = 0; nt < 6; ++nt) {
    float v = h0[nt*16+lr];
    #pragma unroll
    for (int i = 0; i < 4; ++i) { h[nt*4+i] = v; hs[nt*4+i] = 0.f; hm[nt*4+i] = -3.4e38f; }
  }
  __syncthreads();

  const f32x4 zero4 = {0.f, 0.f, 0.f, 0.f};
  const size_t srow_q = (size_t)blockIdx.x*128 + wv*16;    // wave sample base

  for (int t = 0; t < 7; ++t) {
    // ---- (a) write h (bf16) to zg cols 0..95 + C-layout row stats ----
    float hsm[4] = {0.f,0.f,0.f,0.f}, hsq[4] = {0.f,0.f,0.f,0.f};
    #pragma unroll
    for (int nt = 0; nt < 6; ++nt) {
      #pragma unroll
      for (int i = 0; i < 4; ++i) {
        unsigned short hb = f2b(h[nt*4+i]);
        zg[(wv*16 + lq*4 + i)*200 + nt*16 + lr] = hb;
        float hf = b2f(hb);
        hsm[i] += hf; hsq[i] = fmaf(hf, hf, hsq[i]);
      }
    }
    #pragma unroll
    for (int i = 0; i < 4; ++i) {
      hsm[i] += __shfl_xor(hsm[i], 1, 64); hsm[i] += __shfl_xor(hsm[i], 2, 64);
      hsm[i] += __shfl_xor(hsm[i], 4, 64); hsm[i] += __shfl_xor(hsm[i], 8, 64);
      hsq[i] += __shfl_xor(hsq[i], 1, 64); hsq[i] += __shfl_xor(hsq[i], 2, 64);
      hsq[i] += __shfl_xor(hsq[i], 4, 64); hsq[i] += __shfl_xor(hsq[i], 8, 64);
    }
    // ---- (b) combine with precomputed x-stats ----
    float mr[4], rr[4];
    #pragma unroll
    for (int i = 0; i < 4; ++i) {
      const float2 xs = *(const float2*)(xstat + ((srow_q + lq*4 + i)*7 + t)*2);
      float m = (hsm[i] + xs.x) * (1.f/192.f);
      float var = (hsq[i] + xs.y) * (1.f/192.f) - m*m;
      mr[i] = m; rr[i] = rsqrtf(var + 1e-5f);
    }
    // ---- (c) fc1 GEMM: A = [h from LDS | x from global] ----
    bf16x8 ax[3];
    {
      const unsigned short* xp = xrow + ((srow_q + lr)*7 + t)*96;
      #pragma unroll
      for (int k3 = 0; k3 < 3; ++k3)
        ax[k3] = *(const bf16x8*)(xp + k3*32 + lq*8);
    }
    f32x4 acc[12];
    #pragma unroll
    for (int nt = 0; nt < 12; ++nt) acc[nt] = zero4;
    #pragma unroll
    for (int ks = 0; ks < 3; ++ks) {
      bf16x8 a = *(const bf16x8*)(zg + rowt*200 + ks*32 + lq*8);
      #pragma unroll
      for (int nt = 0; nt < 12; ++nt)
        acc[nt] = __builtin_amdgcn_mfma_f32_16x16x32_bf16(a, f1v[(nt*6+ks)*64 + l], acc[nt], 0, 0, 0);
    }
    #pragma unroll
    for (int k3 = 0; k3 < 3; ++k3) {
      #pragma unroll
      for (int nt = 0; nt < 12; ++nt)
        acc[nt] = __builtin_amdgcn_mfma_f32_16x16x32_bf16(ax[k3], f1v[(nt*6+k3+3)*64 + l], acc[nt], 0, 0, 0);
    }
    // ---- (d) LN-finish + gelu -> g (cols 0..191) ----
    #pragma unroll
    for (int nt = 0; nt < 12; ++nt) {
      #pragma unroll
      for (int i = 0; i < 4; ++i) {
        float hid = rr[i]*(acc[nt][i] - mr[i]*C1[nt]) + B1[nt];
        zg[(wv*16 + lq*4 + i)*200 + nt*16 + lr] = f2b(geluf(hid));
      }
    }
    // ---- (e) fc2 GEMM ----
    f32x4 a2[6];
    #pragma unroll
    for (int nt = 0; nt < 6; ++nt) a2[nt] = zero4;
    #pragma unroll
    for (int ks = 0; ks < 6; ++ks) {
      bf16x8 a = *(const bf16x8*)(zg + rowt*200 + ks*32 + lq*8);
      #pragma unroll
      for (int nt = 0; nt < 6; ++nt)
        a2[nt] = __builtin_amdgcn_mfma_f32_16x16x32_bf16(a, f2v[(nt*6+ks)*64 + l], a2[nt], 0, 0, 0);
    }
    // ---- (f) h update ----
    #pragma unroll
    for (int nt = 0; nt < 6; ++nt) {
      #pragma unroll
      for (int i = 0; i < 4; ++i) {
        int u = nt*4 + i;
        h[u] += a2[nt][i] + fb2[nt];
        hs[u] += h[u];
        hm[u] = fmaxf(hm[u], h[u]);
      }
    }
  }
  // ---- feat out + z-stat finalize (k1ab wrote s64 partial first) ----
  float st[4] = {0.f,0.f,0.f,0.f}, qt[4] = {0.f,0.f,0.f,0.f};
  #pragma unroll
  for (int nt = 0; nt < 6; ++nt) {
    #pragma unroll
    for (int i = 0; i < 4; ++i) {
      size_t r = (srow_q + lq*4 + i)*288;
      int c = nt*16 + lr;
      unsigned short b0 = f2b(h[nt*4+i]);
      unsigned short b1 = f2b(hs[nt*4+i]*(1.f/7.f));
      unsigned short b2v = f2b(hm[nt*4+i]);
      feat[r + c] = b0;
      feat[r + 96 + c] = b1;
      feat[r + 192 + c] = b2v;
      float f0 = b2f(b0), f1 = b2f(b1), f2v = b2f(b2v);
      st[i] += f0 + f1 + f2v;
      qt[i] = fmaf(f0, f0, fmaf(f1, f1, fmaf(f2v, f2v, qt[i])));
    }
  }
  #pragma unroll
  for (int i = 0; i < 4; ++i) {
    st[i] += __shfl_xor(st[i], 1, 64); st[i] += __shfl_xor(st[i], 2, 64);
    st[i] += __shfl_xor(st[i], 4, 64); st[i] += __shfl_xor(st[i], 8, 64);
    qt[i] += __shfl_xor(qt[i], 1, 64); qt[i] += __shfl_xor(qt[i], 2, 64);
    qt[i] += __shfl_xor(qt[i], 4, 64); qt[i] += __shfl_xor(qt[i], 8, 64);
  }
  if (lr == 0) {
    #pragma unroll
    for (int i = 0; i < 4; ++i) {
      size_t r = srow_q + lq*4 + i;
      float2 fs = *(float2*)(statg + r*2);         // k1ab partial (ss, qq)
      float stot = fs.x + st[i], qtot = fs.y + qt[i];
      float m = stot*(1.f/352.f);
      float var = qtot*(1.f/352.f) - m*m;
      float2 o; o.x = m; o.y = rsqrtf(var + 1e-5f);
      *(float2*)(statg + r*2) = o;
    }
  }
}

// =================== K2b: heads, weights resident in LDS ===================
// grid (64,3): 192 blocks <= 256 CUs, 4 chunks each -- balanced, no tail.
__global__ __launch_bounds__(512, 2) void k2b_heads(
    const float* __restrict__ hm2_b, const float* __restrict__ hq2_b,
    const float* __restrict__ hn2_b, const char* __restrict__ wsb,
    const unsigned short* __restrict__ feat, float* __restrict__ out)
{
  extern __shared__ char smem[];
  const int g = blockIdx.y;
  const int tid = threadIdx.x;
  const int wv = tid >> 6, l = tid & 63, lr = l & 15, lq = l >> 4;
  const int ntn = (g == 2) ? 6 : 12;
  {
    const uint4* src = (const uint4*)(wsb + O_HDFR + (size_t)g*135168);
    uint4* dst = (uint4*)smem;
    const int n = ntn*11*64;
    for (int o = tid; o < n; o += 512) dst[o] = src[o];
  }
  __syncthreads();
  const bf16x8* wfr = (const bf16x8*)smem;
  const float* hdC = (const float*)(wsb + O_HDC);
  const float* hdB = (const float*)(wsb + O_HDBP);
  const float* w2c = (const float*)(wsb + O_W2C);
  const float* stat = (const float*)(wsb + O_STAT);
  const float* baseb = (const float*)(wsb + O_BASE);
  const unsigned short* s64p = (const unsigned short*)(wsb + O_S64);
  const float hb = (g == 0) ? hm2_b[0] : (g == 1) ? hq2_b[0] : hn2_b[0];
  const f32x4 zero4 = {0.f, 0.f, 0.f, 0.f};

  for (int c = blockIdx.x; c < 256; c += gridDim.x) {
    const int base = c*256 + wv*32;
    bf16x8 afr0[11], afr1[11];
    {
      const unsigned short* fr0 = feat + (size_t)(base + lr)*288;
      const unsigned short* fr1 = feat + (size_t)(base + 16 + lr)*288;
      #pragma unroll
      for (int ks = 0; ks < 9; ++ks) {
        afr0[ks] = *(const bf16x8*)(fr0 + ks*32 + lq*8);
        afr1[ks] = *(const bf16x8*)(fr1 + ks*32 + lq*8);
      }
      const unsigned short* sr0 = s64p + (size_t)(base + lr)*64;
      const unsigned short* sr1 = s64p + (size_t)(base + 16 + lr)*64;
      afr0[9]  = *(const bf16x8*)(sr0 + lq*8);
      afr0[10] = *(const bf16x8*)(sr0 + 32 + lq*8);
      afr1[9]  = *(const bf16x8*)(sr1 + lq*8);
      afr1[10] = *(const bf16x8*)(sr1 + 32 + lq*8);
    }
    float mr0[4], rr0[4], mr1[4], rr1[4];
    #pragma unroll
    for (int i = 0; i < 4; ++i) {
      float2 s0 = *(const float2*)(stat + (size_t)(base + lq*4 + i)*2);
      float2 s1 = *(const float2*)(stat + (size_t)(base + 16 + lq*4 + i)*2);
      mr0[i] = s0.x; rr0[i] = s0.y; mr1[i] = s1.x; rr1[i] = s1.y;
    }
    float pr0[4] = {0.f,0.f,0.f,0.f}, pr1[4] = {0.f,0.f,0.f,0.f};
    for (int nt = 0; nt < ntn; ++nt) {
      const int col = (g*12 + nt)*16 + lr;
      const float Cv = hdC[col], Bv = hdB[col], w2v = w2c[col];
      f32x4 a0 = zero4, a1v = zero4;
      #pragma unroll
      for (int ks = 0; ks < 11; ++ks) {
        bf16x8 b = wfr[(nt*11 + ks)*64 + l];
        a0  = __builtin_amdgcn_mfma_f32_16x16x32_bf16(afr0[ks], b, a0, 0, 0, 0);
        a1v = __builtin_amdgcn_mfma_f32_16x16x32_bf16(afr1[ks], b, a1v, 0, 0, 0);
      }
      #pragma unroll
      for (int i = 0; i < 4; ++i) {
        pr0[i] += geluf(rr0[i]*(a0[i]  - mr0[i]*Cv) + Bv) * w2v;
        pr1[i] += geluf(rr1[i]*(a1v[i] - mr1[i]*Cv) + Bv) * w2v;
      }
    }
    #pragma unroll
    for (int i = 0; i < 4; ++i) {
      float v0 = pr0[i], v1 = pr1[i];
      v0 += __shfl_xor(v0, 1, 64); v0 += __shfl_xor(v0, 2, 64);
      v0 += __shfl_xor(v0, 4, 64); v0 += __shfl_xor(v0, 8, 64);
      v1 += __shfl_xor(v1, 1, 64); v1 += __shfl_xor(v1, 2, 64);
      v1 += __shfl_xor(v1, 4, 64); v1 += __shfl_xor(v1, 8, 64);
      if (lr == 0) {
        int r0 = base + lq*4 + i;
        int r1 = base + 16 + lq*4 + i;
        float b0 = (g < 2) ? baseb[r0] : 0.f;
        float b1 = (g < 2) ? baseb[r1] : 0.f;
        out[(size_t)g*NB + r0] = b0 + hb + v0;
        out[(size_t)g*NB + r1] = b1 + hb + v1;
      }
    }
  }
}

extern "C" void kernel_launch(void* const* d_in, const int* in_sizes, int n_in,
                              void* d_out, int out_size, void* d_ws, size_t ws_size,
                              hipStream_t stream) {
  (void)in_sizes; (void)n_in; (void)out_size; (void)ws_size;
  const float* x_num    = (const float*)d_in[0];
  const float* x_static = (const float*)d_in[1];
  const int*   x_cat    = (const int*)  d_in[2];
  const float* cat_emb  = (const float*)d_in[3];
  const float* day_emb  = (const float*)d_in[4];
  const float* xproj_w  = (const float*)d_in[5];
  const float* xproj_b  = (const float*)d_in[6];
  const float* h0       = (const float*)d_in[7];
  const float* bln_g    = (const float*)d_in[8];
  const float* bln_b    = (const float*)d_in[9];
  const float* fc1_w    = (const float*)d_in[10];
  const float* fc1_b    = (const float*)d_in[11];
  const float* fc2_w    = (const float*)d_in[12];
  const float* fc2_b    = (const float*)d_in[13];
  const float* spln_g   = (const float*)d_in[14];
  const float* spln_b   = (const float*)d_in[15];
  const float* sp1_w    = (const float*)d_in[16];
  const float* sp1_b    = (const float*)d_in[17];
  const float* sp2_w    = (const float*)d_in[18];
  const float* sp2_b    = (const float*)d_in[19];
  const float* base_w   = (const float*)d_in[20];
  const float* base_b   = (const float*)d_in[21];
  const float* hln_g    = (const float*)d_in[22];
  const float* hln_b    = (const float*)d_in[23];
  const float* hm1_w    = (const float*)d_in[24];
  const float* hm1_b    = (const float*)d_in[25];
  const float* hm2_w    = (const float*)d_in[26];
  const float* hm2_b    = (const float*)d_in[27];
  const float* hq1_w    = (const float*)d_in[28];
  const float* hq1_b    = (const float*)d_in[29];
  const float* hq2_w    = (const float*)d_in[30];
  const float* hq2_b    = (const float*)d_in[31];
  const float* hn1_w    = (const float*)d_in[32];
  const float* hn1_b    = (const float*)d_in[33];
  const float* hn2_w    = (const float*)d_in[34];
  const float* hn2_b    = (const float*)d_in[35];

  char* wsb = (char*)d_ws;
  unsigned short* feat = (unsigned short*)(wsb + O_FEAT);
  unsigned short* xrow = (unsigned short*)(wsb + O_XROW);
  float* xstat = (float*)(wsb + O_XSTAT);
  float* statg = (float*)(wsb + O_STAT);
  float* out = (float*)d_out;

  k0_pre<<<589, 512, 0, stream>>>(cat_emb, day_emb, xproj_w, xproj_b,
      bln_g, bln_b, fc1_w, fc1_b, fc2_w, spln_g, spln_b, sp1_w, sp1_b, sp2_w,
      hln_g, hln_b, hm1_w, hm1_b, hq1_w, hq1_b, hn1_w, hn1_b,
      hm2_w, hq2_w, hn2_w, wsb);
  k1ab<<<4608, 256, 0, stream>>>(x_num, x_cat, x_static, sp2_b, base_w, base_b,
      wsb, xrow, xstat);
  k1_scan<<<512, 512, 161792, stream>>>(h0, fc2_b, wsb, xrow, xstat, feat, statg);
  k2b_heads<<<dim3(64, 3), 512, 135168, stream>>>(hm2_b, hq2_b, hn2_b,
      wsb, feat, out);
}